// Round 10
// baseline (351.565 us; speedup 1.0000x reference)
//
#include <hip/hip_runtime.h>
#include <hip/hip_cooperative_groups.h>

namespace cg = cooperative_groups;

#define S 32
#define E 48
#define H 512
#define L 16

typedef float vf4 __attribute__((ext_vector_type(4)));

// ws layout (floats): [0, S*E*L) xb : exp(2*b[s,e,l] + bias[l] - p2[l])
// Cooperative path keeps xa in LDS; fallback path also stores xa at ws+S*E*L.

__device__ __forceinline__ void phase1_compute(const float* __restrict__ emb,
                                               const float* __restrict__ proto,
                                               const float* __restrict__ ic,
                                               int se, int wid, int lane,
                                               float* __restrict__ xa_out,   // LDS or global
                                               float* __restrict__ xb_out) { // global
    const float* er = emb + (size_t)se * H;
    float4 ev0 = *reinterpret_cast<const float4*>(er + 4 * lane);
    float4 ev1 = *reinterpret_cast<const float4*>(er + 256 + 4 * lane);

    float my_a = 0.f, my_b = 0.f, my_p = 0.f;
#pragma unroll
    for (int i = 0; i < 4; ++i) {
        int l = wid * 4 + i;                            // wave w owns l = 4w..4w+3
        const float* ph = proto + (size_t)l * (2 * H);  // head [0,512)
        const float* pt = ph + H;                       // tail [512,1024)
        float4 h0 = *reinterpret_cast<const float4*>(ph + 4 * lane);
        float4 h1 = *reinterpret_cast<const float4*>(ph + 256 + 4 * lane);
        float4 t0 = *reinterpret_cast<const float4*>(pt + 4 * lane);
        float4 t1 = *reinterpret_cast<const float4*>(pt + 256 + 4 * lane);
        float da = ev0.x * h0.x + ev0.y * h0.y + ev0.z * h0.z + ev0.w * h0.w
                 + ev1.x * h1.x + ev1.y * h1.y + ev1.z * h1.z + ev1.w * h1.w;
        float db = ev0.x * t0.x + ev0.y * t0.y + ev0.z * t0.z + ev0.w * t0.w
                 + ev1.x * t1.x + ev1.y * t1.y + ev1.z * t1.z + ev1.w * t1.w;
        float dp = h0.x * h0.x + h0.y * h0.y + h0.z * h0.z + h0.w * h0.w
                 + h1.x * h1.x + h1.y * h1.y + h1.z * h1.z + h1.w * h1.w
                 + t0.x * t0.x + t0.y * t0.y + t0.z * t0.z + t0.w * t0.w
                 + t1.x * t1.x + t1.y * t1.y + t1.z * t1.z + t1.w * t1.w;
#pragma unroll
        for (int m = 32; m >= 1; m >>= 1) {
            da += __shfl_xor(da, m);
            db += __shfl_xor(db, m);
            dp += __shfl_xor(dp, m);
        }
        if (lane == i) { my_a = da; my_b = db; my_p = dp; }
    }
    if (lane < 4) {
        int l = wid * 4 + lane;
        float total = 0.f;
#pragma unroll
        for (int k = 0; k < L; ++k) total += ic[k];
        float icl  = ic[l];
        float bias = icl / (total - icl);
        xa_out[l] = __expf(2.f * my_a);
        xb_out[l] = __expf(2.f * my_b + bias - my_p);
    }
}

__device__ __forceinline__ void phase2_stream(const float* __restrict__ xa_row,
                                              const float* __restrict__ xb_panel,
                                              float* __restrict__ out,
                                              int b, int e1, int wid, int lane, int t) {
    int c = lane & 3;              // which float4 of the 16-float pattern
    const vf4* xa4 = reinterpret_cast<const vf4*>(xa_row);
    vf4 a0 = xa4[0], a1 = xa4[1], a2 = xa4[2], a3 = xa4[3];
    vf4 ac = (c == 0) ? a0 : (c == 1) ? a1 : (c == 2) ? a2 : a3;

    const vf4* xb4 = reinterpret_cast<const vf4*>(xb_panel);
    vf4* o4 = reinterpret_cast<vf4*>(out) + (size_t)b * E * 64;

#pragma unroll 3
    for (int j = 0; j < 12; ++j) {
        int e2 = 4 * j + wid;
        const vf4* xr = xb4 + e2 * 4;
        vf4 b0 = xr[0], b1 = xr[1], b2 = xr[2], b3 = xr[3];
        vf4 ps = a0 * b0 + a1 * b1 + a2 * b2 + a3 * b3;
        float sum = ps.x + ps.y + ps.z + ps.w;
        float inv = (e2 == e1) ? 0.f : 1.f / sum;   // diagonal -> zero row
        vf4 bc = (c == 0) ? b0 : (c == 1) ? b1 : (c == 2) ? b2 : b3;
        vf4 v = ac * bc * inv;
        __builtin_nontemporal_store(v, o4 + (j * 256 + t));
    }
}

// ---- cooperative single-dispatch version ----
__global__ __launch_bounds__(256, 6) void fused(const float* __restrict__ emb,
                                                const float* __restrict__ proto,
                                                const float* __restrict__ ic,
                                                float* __restrict__ xb,
                                                float* __restrict__ out) {
    int b    = blockIdx.x;         // 0..1535 == se == s*E + e1
    int t    = threadIdx.x;
    int wid  = t >> 6;
    int lane = t & 63;

    __shared__ float sxa[L];
    phase1_compute(emb, proto, ic, b, wid, lane, sxa, xb + (size_t)b * L);

    __threadfence();               // release xb stores at device scope
    cg::this_grid().sync();        // also orders sxa for this block

    int s  = b / E;
    int e1 = b - s * E;
    phase2_stream(sxa, xb + (size_t)s * E * L, out, b, e1, wid, lane, t);
}

// ---- fallback two-dispatch version ----
__global__ __launch_bounds__(256) void k1_only(const float* __restrict__ emb,
                                               const float* __restrict__ proto,
                                               const float* __restrict__ ic,
                                               float* __restrict__ xa,
                                               float* __restrict__ xb) {
    int b    = blockIdx.x;
    int wid  = threadIdx.x >> 6;
    int lane = threadIdx.x & 63;
    phase1_compute(emb, proto, ic, b, wid, lane,
                   xa + (size_t)b * L, xb + (size_t)b * L);
}

__global__ __launch_bounds__(256) void k2_only(const float* __restrict__ xa,
                                               const float* __restrict__ xb,
                                               float* __restrict__ out) {
    int b    = blockIdx.x;
    int t    = threadIdx.x;
    int wid  = t >> 6;
    int lane = t & 63;
    int s  = b / E;
    int e1 = b - s * E;
    __shared__ float sxa[L];
    if (t < L) sxa[t] = xa[(size_t)b * L + t];
    __syncthreads();
    phase2_stream(sxa, xb + (size_t)s * E * L, out, b, e1, wid, lane, t);
}

extern "C" void kernel_launch(void* const* d_in, const int* in_sizes, int n_in,
                              void* d_out, int out_size, void* d_ws, size_t ws_size,
                              hipStream_t stream) {
    const float* emb   = (const float*)d_in[0];   // (S,E,H)
    const float* proto = (const float*)d_in[1];   // (L,2H)
    const float* ic    = (const float*)d_in[2];   // (L,)
    float* out = (float*)d_out;
    float* xb  = (float*)d_ws;
    float* xa  = (float*)d_ws + S * E * L;

    void* args[] = { (void*)&emb, (void*)&proto, (void*)&ic, (void*)&xb, (void*)&out };
    hipError_t err = hipLaunchCooperativeKernel((const void*)fused, dim3(S * E),
                                                dim3(256), args, 0, stream);
    if (err != hipSuccess) {
        // deterministic fallback: same math, two dispatches
        k1_only<<<S * E, 256, 0, stream>>>(emb, proto, ic, xa, xb);
        k2_only<<<S * E, 256, 0, stream>>>(xa, xb, out);
    }
}

// Round 12
// 120.440 us; speedup vs baseline: 2.9190x; 2.9190x over previous
//
#include <hip/hip_runtime.h>

#define S 32
#define E 48
#define H 512
#define L 16
#define E1PB 6   // e1 rows per block (48/8 groups)

typedef float vf4 __attribute__((ext_vector_type(4)));

// Single dispatch: 256 blocks (1 per CU), 512 threads (8 waves).
// Block (s,g) owns e1 = g*6 .. g*6+5 and computes everything it needs in LDS:
//   xb panel (48 rows), xa rows (6), p2/bias stat. Then streams 288 KB out.
__global__ __launch_bounds__(512) void fused_all(const float* __restrict__ emb,
                                                 const float* __restrict__ proto,
                                                 const float* __restrict__ ic,
                                                 float* __restrict__ out) {
    int bid  = blockIdx.x;          // 0..255
    int s    = bid >> 3;            // 0..31
    int g    = bid & 7;             // 0..7
    int t    = threadIdx.x;         // 0..511
    int wid  = t >> 6;              // 0..7
    int lane = t & 63;
    int l    = lane & 15;           // prototype index this lane reduces
    int seg  = lane >> 4;           // 0..3 : 128-elem segment of H

    __shared__ __align__(16) float xb_s[E][L];     // raw 2b -> exp(2b+stat)
    __shared__ __align__(16) float xa_s[E1PB][L];  // raw 2a -> exp(2a)
    __shared__ float sstat[L];                     // bias[l] - p2[l]
    __shared__ float sinv[E1PB][E];                // 1/den (0 on diagonal)

    const float* embS = emb + (size_t)s * E * H;

    // ---- phase A: 19 wave-tasks over 3 rounds ----
    for (int rnd = 0; rnd < 3; ++rnd) {
        int task = rnd * 8 + wid;
        if (task < 16) {
            // xb triple: rows e2 = 3*task..3*task+2, dot vs proto_tail[l]
            const float* pp = proto + (size_t)l * (2 * H) + H + seg * 128;
            const float* r0 = embS + (size_t)(3 * task + 0) * H + seg * 128;
            const float* r1 = embS + (size_t)(3 * task + 1) * H + seg * 128;
            const float* r2 = embS + (size_t)(3 * task + 2) * H + seg * 128;
            float s0 = 0.f, s1 = 0.f, s2 = 0.f;
#pragma unroll 4
            for (int k = 0; k < 128; k += 4) {
                float4 p = *reinterpret_cast<const float4*>(pp + k);
                float4 a = *reinterpret_cast<const float4*>(r0 + k);
                float4 b = *reinterpret_cast<const float4*>(r1 + k);
                float4 c = *reinterpret_cast<const float4*>(r2 + k);
                s0 += p.x*a.x + p.y*a.y + p.z*a.z + p.w*a.w;
                s1 += p.x*b.x + p.y*b.y + p.z*b.z + p.w*b.w;
                s2 += p.x*c.x + p.y*c.y + p.z*c.z + p.w*c.w;
            }
            s0 += __shfl_xor(s0, 16); s0 += __shfl_xor(s0, 32);
            s1 += __shfl_xor(s1, 16); s1 += __shfl_xor(s1, 32);
            s2 += __shfl_xor(s2, 16); s2 += __shfl_xor(s2, 32);
            if (seg == 0) {
                xb_s[3 * task + 0][l] = 2.f * s0;
                xb_s[3 * task + 1][l] = 2.f * s1;
                xb_s[3 * task + 2][l] = 2.f * s2;
            }
        } else if (task < 18) {
            // xa triple: local rows 3*(task-16)..+2, dot vs proto_head[l]
            int t2 = task - 16;
            const float* pp = proto + (size_t)l * (2 * H) + seg * 128;
            const float* r0 = embS + (size_t)(g * E1PB + 3 * t2 + 0) * H + seg * 128;
            const float* r1 = embS + (size_t)(g * E1PB + 3 * t2 + 1) * H + seg * 128;
            const float* r2 = embS + (size_t)(g * E1PB + 3 * t2 + 2) * H + seg * 128;
            float s0 = 0.f, s1 = 0.f, s2 = 0.f;
#pragma unroll 4
            for (int k = 0; k < 128; k += 4) {
                float4 p = *reinterpret_cast<const float4*>(pp + k);
                float4 a = *reinterpret_cast<const float4*>(r0 + k);
                float4 b = *reinterpret_cast<const float4*>(r1 + k);
                float4 c = *reinterpret_cast<const float4*>(r2 + k);
                s0 += p.x*a.x + p.y*a.y + p.z*a.z + p.w*a.w;
                s1 += p.x*b.x + p.y*b.y + p.z*b.z + p.w*b.w;
                s2 += p.x*c.x + p.y*c.y + p.z*c.z + p.w*c.w;
            }
            s0 += __shfl_xor(s0, 16); s0 += __shfl_xor(s0, 32);
            s1 += __shfl_xor(s1, 16); s1 += __shfl_xor(s1, 32);
            s2 += __shfl_xor(s2, 16); s2 += __shfl_xor(s2, 32);
            if (seg == 0) {
                xa_s[3 * t2 + 0][l] = 2.f * s0;
                xa_s[3 * t2 + 1][l] = 2.f * s1;
                xa_s[3 * t2 + 2][l] = 2.f * s2;
            }
        } else if (task == 18) {
            // p2[l] over full 1024-elem proto row, + bias -> sstat
            const float* pp = proto + (size_t)l * (2 * H) + seg * 256;
            float q = 0.f;
#pragma unroll 4
            for (int k = 0; k < 256; k += 4) {
                float4 p = *reinterpret_cast<const float4*>(pp + k);
                q += p.x*p.x + p.y*p.y + p.z*p.z + p.w*p.w;
            }
            q += __shfl_xor(q, 16); q += __shfl_xor(q, 32);
            if (seg == 0) {
                float tot = 0.f;
#pragma unroll
                for (int k = 0; k < L; ++k) tot += ic[k];
                float icl = ic[l];
                sstat[l] = icl / (tot - icl) - q;
            }
        }
    }
    __syncthreads();

    // ---- exp pass (in place) ----
    {
        float* fb = &xb_s[0][0];                    // 768 values
        fb[t] = __expf(fb[t] + sstat[t & 15]);
        if (t < 256) fb[t + 512] = __expf(fb[t + 512] + sstat[t & 15]);
        float* fa = &xa_s[0][0];                    // 96 values
        if (t < 96) fa[t] = __expf(fa[t]);
    }
    __syncthreads();

    // ---- denominators: 288 (i,e2) pairs ----
    if (t < E1PB * E) {
        int i  = t / E;
        int e2 = t - i * E;
        float den = 0.f;
#pragma unroll
        for (int k = 0; k < L; ++k) den += xa_s[i][k] * xb_s[e2][k];
        int e1 = g * E1PB + i;
        sinv[i][e2] = (e2 == e1) ? 0.f : 1.f / den;
    }
    __syncthreads();

    // ---- store: 6 slabs x 48 rows x 64 float4 = 288 KB contiguous ----
    vf4* o4 = reinterpret_cast<vf4*>(out) + (size_t)(s * E + g * E1PB) * E * 64;
    int c = lane & 3;               // which float4 of the 16-float pattern
#pragma unroll
    for (int i = 0; i < E1PB; ++i) {
        vf4 a4 = reinterpret_cast<const vf4*>(&xa_s[i][0])[c];
#pragma unroll
        for (int j = 0; j < 6; ++j) {
            int f  = j * 512 + t;                  // 0..3071 within slab
            int e2 = f >> 6;                       // wave-uniform row
            vf4 b4 = reinterpret_cast<const vf4*>(&xb_s[e2][0])[c];
            vf4 v  = a4 * b4 * sinv[i][e2];
            __builtin_nontemporal_store(v, o4 + (size_t)i * 3072 + f);
        }
    }
}

extern "C" void kernel_launch(void* const* d_in, const int* in_sizes, int n_in,
                              void* d_out, int out_size, void* d_ws, size_t ws_size,
                              hipStream_t stream) {
    const float* emb   = (const float*)d_in[0];   // (S,E,H)
    const float* proto = (const float*)d_in[1];   // (L,2H)
    const float* ic    = (const float*)d_in[2];   // (L,)
    float* out = (float*)d_out;

    fused_all<<<S * 8, 512, 0, stream>>>(emb, proto, ic, out);
}